// Round 1
// baseline (217.121 us; speedup 1.0000x reference)
//
#include <hip/hip_runtime.h>

#define NG 40

// ---------- pre-kernel: K2[g] = k[g] (full 2-D conv) k[g], 9x9 per group ----------
// Two circular cross-correlations with k == one circular cross-correlation with K2.
__global__ void compose_k2(const float* __restrict__ kernels, float* __restrict__ k2) {
    int t = blockIdx.x * 256 + threadIdx.x;          // 40*81 = 3240 outputs
    if (t >= NG * 81) return;
    int gi = t / 81, r = t - gi * 81;
    int a = r / 9, b = r - a * 9;
    const float* k = kernels + gi * 25;
    float s = 0.f;
    for (int i = 0; i < 5; ++i) {
        int p = a - i;
        if (p < 0 || p > 4) continue;
        for (int j = 0; j < 5; ++j) {
            int q = b - j;
            if (q < 0 || q > 4) continue;
            s += k[i * 5 + j] * k[p * 5 + q];
        }
    }
    k2[t] = s;
}

__device__ __forceinline__ void async_copy16(const float* gsrc, float* lds_dst) {
    __builtin_amdgcn_global_load_lds(
        (const __attribute__((address_space(1))) void*)(gsrc),
        (__attribute__((address_space(3))) void*)(lds_dst),
        16, 0, 0);
}

// ---------- main kernel: one 56x56 plane per block ----------
// LDS tile: 64 padded rows x 64 padded cols (halo 4 each side, circular).
// BANK-CONFLICT FIX (this revision): 16B-segment XOR swizzle by row.
//   logical (row, seg) is stored at physical (row, seg ^ (row & 7)).
// Rows are 256B (a full bank sweep), so un-swizzled reads put ~9 lanes with
// distinct addresses on the same 4-bank group per read (SQ_LDS_BANK_CONFLICT
// = 1.87e7, ~25 extra cyc per ds_read). global_load_lds writes linearly, so
// the swizzle is applied on the SOURCE address at staging and identically on
// the compute-side read address (both-sides-or-neither).
// Thread p (< 112) computes a 7-row x 4-col output patch:
//   rows q..q+6 (q = 7*(p/14)), cols c..c+3 (c = 4*(p%14)).
template <bool USE_WS>
__global__ __launch_bounds__(128, 3)
void conv9_main(const float* __restrict__ x, const float* __restrict__ kdata,
                const int* __restrict__ g, float* __restrict__ out) {
    __shared__ float tile[64 * 64];
    __shared__ float k9s[84];

    const int tid = threadIdx.x;
    const int bx  = blockIdx.x;          // == b*64 + channel, 8192 blocks
    const int b   = bx >> 6;

    int gi = g[b] % NG; if (gi < 0) gi += NG;

    // --- stage plane into LDS via async global->LDS, 16B/lane ---
    // Physical slot (pr, seg) receives logical segment (seg ^ (pr & 7)).
    const float* xp = x + (size_t)bx * 3136;
    #pragma unroll
    for (int m = 0; m < 8; ++m) {
        int idx = m * 128 + tid;         // 0..1023 = padded row*16 + phys seg
        int pr  = idx >> 4;
        int seg = idx & 15;
        int lseg = seg ^ (pr & 7);       // logical segment for this slot
        int sr = pr - 4;       if (sr < 0) sr += 56; if (sr >= 56) sr -= 56;
        int sc = lseg * 4 - 4; if (sc < 0) sc += 56; if (sc >= 56) sc -= 56;
        async_copy16(xp + sr * 56 + sc, tile + idx * 4);
    }

    // --- composed 9x9 taps ---
    float kk[81];
    if (USE_WS) {
        const float* kp = kdata + gi * 81;   // uniform address -> scalar loads
        #pragma unroll
        for (int i = 0; i < 81; ++i) kk[i] = kp[i];
    } else {
        if (tid < 81) {
            const float* k = kdata + gi * 25;
            int a = tid / 9, bb = tid - a * 9;
            float s = 0.f;
            for (int i = 0; i < 5; ++i) {
                int p = a - i;
                if (p < 0 || p > 4) continue;
                for (int j = 0; j < 5; ++j) {
                    int q = bb - j;
                    if (q < 0 || q > 4) continue;
                    s += k[i * 5 + j] * k[p * 5 + q];
                }
            }
            k9s[tid] = s;
        }
    }

    __syncthreads();   // drains vmcnt (global_load_lds) + lds writes

    if (!USE_WS) {
        #pragma unroll
        for (int i = 0; i < 81; ++i) kk[i] = k9s[i];   // broadcast reads
    }

    const int p = tid;
    if (p < 112) {
        const int pr = p / 14;            // 0..7  -> q = 7*pr
        const int pc = p - pr * 14;       // 0..13 -> c = 4*pc
        const int q  = 7 * pr;
        const int c  = 4 * pc;
        const int eq = q & 7;             // row-swizzle phase of this thread

        float acc[7][4] = {};

        #pragma unroll
        for (int h = 0; h < 15; ++h) {
            // 12-float window of padded row q+h, logical cols c..c+11.
            // Physical 16B segment = logical segment XOR (row & 7).
            const int e = (eq + h) & 7;
            const float* rbase = tile + (q + h) * 64;
            float4 A = *(const float4*)(rbase + (((pc + 0) ^ e) << 2));
            float4 B = *(const float4*)(rbase + (((pc + 1) ^ e) << 2));
            float4 C = *(const float4*)(rbase + (((pc + 2) ^ e) << 2));
            float w[12] = {A.x, A.y, A.z, A.w, B.x, B.y, B.z, B.w, C.x, C.y, C.z, C.w};
            #pragma unroll
            for (int ro = 0; ro < 7; ++ro) {
                const int v = h - ro;         // kernel row tap
                if (v < 0 || v > 8) continue; // folded at compile time
                #pragma unroll
                for (int j = 0; j < 4; ++j) {
                    #pragma unroll
                    for (int u = 0; u < 9; ++u)
                        acc[ro][j] += w[j + u] * kk[v * 9 + u];
                }
            }
        }

        float* op = out + (size_t)bx * 3136 + q * 56 + c;
        #pragma unroll
        for (int ro = 0; ro < 7; ++ro)
            *(float4*)(op + ro * 56) =
                make_float4(acc[ro][0], acc[ro][1], acc[ro][2], acc[ro][3]);
    }
}

extern "C" void kernel_launch(void* const* d_in, const int* in_sizes, int n_in,
                              void* d_out, int out_size, void* d_ws, size_t ws_size,
                              hipStream_t stream) {
    const float* x    = (const float*)d_in[0];
    const float* kern = (const float*)d_in[1];
    const int*   g    = (const int*)d_in[2];
    float*       out  = (float*)d_out;

    const bool use_ws = ws_size >= (size_t)(NG * 81 * sizeof(float));
    if (use_ws) {
        compose_k2<<<dim3((NG * 81 + 255) / 256), dim3(256), 0, stream>>>(kern, (float*)d_ws);
        conv9_main<true><<<dim3(8192), dim3(128), 0, stream>>>(x, (const float*)d_ws, g, out);
    } else {
        conv9_main<false><<<dim3(8192), dim3(128), 0, stream>>>(x, kern, g, out);
    }
}

// Round 2
// 216.173 us; speedup vs baseline: 1.0044x; 1.0044x over previous
//
#include <hip/hip_runtime.h>

#define NG 40

// ---------- pre-kernel: K2[g] = k[g] (full 2-D conv) k[g], 9x9 per group ----------
// Two circular cross-correlations with k == one circular cross-correlation with K2.
__global__ void compose_k2(const float* __restrict__ kernels, float* __restrict__ k2) {
    int t = blockIdx.x * 256 + threadIdx.x;          // 40*81 = 3240 outputs
    if (t >= NG * 81) return;
    int gi = t / 81, r = t - gi * 81;
    int a = r / 9, b = r - a * 9;
    const float* k = kernels + gi * 25;
    float s = 0.f;
    for (int i = 0; i < 5; ++i) {
        int p = a - i;
        if (p < 0 || p > 4) continue;
        for (int j = 0; j < 5; ++j) {
            int q = b - j;
            if (q < 0 || q > 4) continue;
            s += k[i * 5 + j] * k[p * 5 + q];
        }
    }
    k2[t] = s;
}

__device__ __forceinline__ void async_copy16(const float* gsrc, float* lds_dst) {
    __builtin_amdgcn_global_load_lds(
        (const __attribute__((address_space(1))) void*)(gsrc),
        (__attribute__((address_space(3))) void*)(lds_dst),
        16, 0, 0);
}

// ---------- main kernel: one 56x56 plane per block ----------
// LDS tile: 64 padded rows x 72 padded cols (stride 288B = 18 x 16B segments).
// BANK-CONFLICT FIX (this revision): structural, zero extra VALU.
//   Round-0 (stride 64, 14-wide row groups) put 9 lanes on bank-groups 0-5 and
//   5 on groups 6-7 per wave b128 read (~37 cyc/instr). A row-XOR swizzle only
//   rotates the per-row-group imbalance (r1: conflicts -36%, VALU +48%, net
//   regression). Instead: 8x16 thread grid (pr=tid>>4, pc=tid&15) with an
//   18-segment row. Row-group boundaries now fall on 16-lane boundaries, so
//   EVERY 8 consecutive lanes hit 8 distinct bank groups and the wave is
//   uniform 8 accesses/bank — the m134 conflict-free b128 distribution.
//   Threads pc=14,15 compute discardable columns (same per-wave instruction
//   count as round-0's idle lanes) and skip the store.
//   All 45 ds_read_b128 keep ONE base register + folded offset immediates
//   (max 14*288+32 = 4064 B).
template <bool USE_WS>
__global__ __launch_bounds__(128, 3)
void conv9_main(const float* __restrict__ x, const float* __restrict__ kdata,
                const int* __restrict__ g, float* __restrict__ out) {
    __shared__ float tile[64 * 72];
    __shared__ float k9s[84];

    const int tid = threadIdx.x;
    const int bx  = blockIdx.x;          // == b*64 + channel, 8192 blocks
    const int b   = bx >> 6;

    int gi = g[b] % NG; if (gi < 0) gi += NG;

    // --- stage plane into LDS via async global->LDS, 16B/lane ---
    // Linear LDS fill: idx'th 16B segment = (row idx/18, segment idx%18).
    // Segment s holds padded cols 4s..4s+3 = logical cols 4s-4..4s-1
    // (circularly wrapped; 56 % 4 == 0 so every wrapped 4-run is contiguous).
    const float* xp = x + (size_t)bx * 3136;
    #pragma unroll
    for (int m = 0; m < 9; ++m) {
        int idx = m * 128 + tid;         // 0..1151 = row*18 + seg
        int pr  = idx / 18;
        int seg = idx - pr * 18;
        int sr = pr - 4;      if (sr < 0) sr += 56; if (sr >= 56) sr -= 56;
        int sc = seg * 4 - 4; if (sc < 0) sc += 56; if (sc >= 56) sc -= 56;
        async_copy16(xp + sr * 56 + sc, tile + idx * 4);
    }

    // --- composed 9x9 taps ---
    float kk[81];
    if (USE_WS) {
        const float* kp = kdata + gi * 81;   // uniform address -> scalar loads
        #pragma unroll
        for (int i = 0; i < 81; ++i) kk[i] = kp[i];
    } else {
        if (tid < 81) {
            const float* k = kdata + gi * 25;
            int a = tid / 9, bb = tid - a * 9;
            float s = 0.f;
            for (int i = 0; i < 5; ++i) {
                int p = a - i;
                if (p < 0 || p > 4) continue;
                for (int j = 0; j < 5; ++j) {
                    int q = bb - j;
                    if (q < 0 || q > 4) continue;
                    s += k[i * 5 + j] * k[p * 5 + q];
                }
            }
            k9s[tid] = s;
        }
    }

    __syncthreads();   // drains vmcnt (global_load_lds) + lds writes

    if (!USE_WS) {
        #pragma unroll
        for (int i = 0; i < 81; ++i) kk[i] = k9s[i];   // broadcast reads
    }

    // --- compute: 8x16 thread grid, 7-row x 4-col patch each ---
    const int pr = tid >> 4;             // 0..7  -> q = 7*pr
    const int pc = tid & 15;             // 0..15 -> c = 4*pc (14,15 discarded)
    const int q  = 7 * pr;
    const int c  = 4 * pc;

    float acc[7][4] = {};
    const float* trow = tile + q * 72 + c;   // padded col c = logical col c-4

    #pragma unroll
    for (int h = 0; h < 15; ++h) {
        // 12-float window of padded row q+h, logical cols c-4..c+7
        float4 A = *(const float4*)(trow + h * 72);
        float4 B = *(const float4*)(trow + h * 72 + 4);
        float4 C = *(const float4*)(trow + h * 72 + 8);
        float w[12] = {A.x, A.y, A.z, A.w, B.x, B.y, B.z, B.w, C.x, C.y, C.z, C.w};
        #pragma unroll
        for (int ro = 0; ro < 7; ++ro) {
            const int v = h - ro;         // kernel row tap
            if (v < 0 || v > 8) continue; // folded at compile time
            #pragma unroll
            for (int j = 0; j < 4; ++j) {
                #pragma unroll
                for (int u = 0; u < 9; ++u)
                    acc[ro][j] += w[j + u] * kk[v * 9 + u];
            }
        }
    }

    if (pc < 14) {
        float* op = out + (size_t)bx * 3136 + q * 56 + c;
        #pragma unroll
        for (int ro = 0; ro < 7; ++ro)
            *(float4*)(op + ro * 56) =
                make_float4(acc[ro][0], acc[ro][1], acc[ro][2], acc[ro][3]);
    }
}

extern "C" void kernel_launch(void* const* d_in, const int* in_sizes, int n_in,
                              void* d_out, int out_size, void* d_ws, size_t ws_size,
                              hipStream_t stream) {
    const float* x    = (const float*)d_in[0];
    const float* kern = (const float*)d_in[1];
    const int*   g    = (const int*)d_in[2];
    float*       out  = (float*)d_out;

    const bool use_ws = ws_size >= (size_t)(NG * 81 * sizeof(float));
    if (use_ws) {
        compose_k2<<<dim3((NG * 81 + 255) / 256), dim3(256), 0, stream>>>(kern, (float*)d_ws);
        conv9_main<true><<<dim3(8192), dim3(128), 0, stream>>>(x, (const float*)d_ws, g, out);
    } else {
        conv9_main<false><<<dim3(8192), dim3(128), 0, stream>>>(x, kern, g, out);
    }
}